// Round 4
// baseline (313.631 us; speedup 1.0000x reference)
//
#include <hip/hip_runtime.h>
#include <stdint.h>

#define OUT_F 4096
#define IN_F  4096
#define NGROUPS 32
#define BK 64
#define NT (IN_F / BK)   // 64

typedef __attribute__((ext_vector_type(4)))  float    f32x4;
typedef __attribute__((ext_vector_type(16))) float    f32x16;
typedef __attribute__((ext_vector_type(8)))  short    bf16x8;
typedef __attribute__((ext_vector_type(4)))  int      i32x4;
typedef __attribute__((ext_vector_type(4)))  uint32_t u32x4;

__device__ __forceinline__ ushort f2bf(float f) {
  union { float f; uint32_t u; } v; v.f = f;
  uint32_t r = v.u + 0x7FFFu + ((v.u >> 16) & 1u);
  return (ushort)(r >> 16);
}

// ---- kernel 1: x (f32) -> bf16, 8 elems/thread --------------------------
__global__ void cvt_x_kernel(const float* __restrict__ x, ushort* __restrict__ xb, int n8) {
  int i = blockIdx.x * blockDim.x + threadIdx.x;
  if (i >= n8) return;
  const f32x4* xp = (const f32x4*)x;
  f32x4 a = xp[2 * i], b = xp[2 * i + 1];
  u32x4 o;
  o.x = (uint32_t)f2bf(a.x) | ((uint32_t)f2bf(a.y) << 16);
  o.y = (uint32_t)f2bf(a.z) | ((uint32_t)f2bf(a.w) << 16);
  o.z = (uint32_t)f2bf(b.x) | ((uint32_t)f2bf(b.y) << 16);
  o.w = (uint32_t)f2bf(b.z) | ((uint32_t)f2bf(b.w) << 16);
  ((u32x4*)xb)[i] = o;
}

// ---- kernel 2: dequant weight -> bf16 [OUT_F][IN_F] ----------------------
__global__ void dequant_w_kernel(const int* __restrict__ cw,
                                 const float* __restrict__ sc,
                                 const float* __restrict__ of,
                                 ushort* __restrict__ wb) {
  int t = blockIdx.x * blockDim.x + threadIdx.x;
  int o  = t >> 9;
  int k0 = (t & 511) << 3;
  int g  = k0 >> 7;
  float s   = sc[o * NGROUPS + g];
  float off = of[o * NGROUPS + g];
  const i32x4* cp = (const i32x4*)(cw + (size_t)o * IN_F + k0);
  i32x4 c0 = cp[0], c1 = cp[1];
  u32x4 out;
  out.x = (uint32_t)f2bf((float)c0.x * s - off) | ((uint32_t)f2bf((float)c0.y * s - off) << 16);
  out.y = (uint32_t)f2bf((float)c0.z * s - off) | ((uint32_t)f2bf((float)c0.w * s - off) << 16);
  out.z = (uint32_t)f2bf((float)c1.x * s - off) | ((uint32_t)f2bf((float)c1.y * s - off) << 16);
  out.w = (uint32_t)f2bf((float)c1.z * s - off) | ((uint32_t)f2bf((float)c1.w * s - off) << 16);
  *(u32x4*)(wb + (size_t)o * IN_F + k0) = out;
}

// ---- kernel 3: 256x256 tile, BK=64, 8-wave, 32x32x16 K-slice pipeline ----
// C[M][N] = A[M][K] * B[N][K]^T, bf16 in, f32 out.
// LDS 128KB: [buf(2)][A:32K rows 0..255 | B:32K rows 0..255], row = 128B (8 slots x 16B)
// swizzle: slot_phys = slot_log ^ (row & 7), via pre-swizzled global source.
// Pipeline: per K-tile 4 slices (K=16). Fragment sets F0/F1 ping-pong; slice
// s+1 reads issue before slice s's MFMA cluster -> uniform lead-1 (incl. the
// next tile's s0 read, placed after the beta barrier, covered by s3 MFMAs).
// 2 barriers + 1 counted vmcnt per tile.

#define BAR() do { asm volatile("" ::: "memory"); __builtin_amdgcn_s_barrier(); asm volatile("" ::: "memory"); } while (0)

#define GLLDS(gp, lp) __builtin_amdgcn_global_load_lds( \
  (const __attribute__((address_space(1))) uint32_t*)(const void*)(gp), \
  (__attribute__((address_space(3))) uint32_t*)(void*)(lp), 16, 0, 0)

// stage 256x64 bf16 panel (linear rows, pre-swizzled k-slot in global src)
#define STAGE_A(buf, kt) do { \
  _Pragma("unroll") for (int q_ = 0; q_ < 4; ++q_) \
    GLLDS(A + (size_t)(m0 + q_ * 64 + stRow) * IN_F + (kt) * BK + sl * 8, \
          ldsb + (buf) * 65536 + q_ * 8192 + wid * 1024); \
} while (0)

#define STAGE_B(buf, kt) do { \
  _Pragma("unroll") for (int q_ = 0; q_ < 4; ++q_) \
    GLLDS(B + (size_t)(n0 + q_ * 64 + stRow) * IN_F + (kt) * BK + sl * 8, \
          ldsb + (buf) * 65536 + 32768 + q_ * 8192 + wid * 1024); \
} while (0)

// read one K=16 slice of fragments into set SET from bases (aX, bX)
#define RD_SLICE(SET, S, aX, bX) do { \
  _Pragma("unroll") for (int i_ = 0; i_ < 4; ++i_) \
    A_[SET][i_] = *(const bf16x8*)((aX) + (i_ * 32 + lw) * 128 + kOff[S]); \
  _Pragma("unroll") for (int j_ = 0; j_ < 2; ++j_) \
    B_[SET][j_] = *(const bf16x8*)((bX) + (j_ * 32 + lw) * 128 + kOff[S]); \
} while (0)

#define MFMA_SLICE(SET) do { \
  __builtin_amdgcn_s_setprio(1); \
  _Pragma("unroll") for (int i_ = 0; i_ < 4; ++i_) \
  _Pragma("unroll") for (int j_ = 0; j_ < 2; ++j_) \
    acc[i_][j_] = __builtin_amdgcn_mfma_f32_32x32x16_bf16(A_[SET][i_], B_[SET][j_], acc[i_][j_], 0, 0, 0); \
  __builtin_amdgcn_s_setprio(0); \
} while (0)

__global__ __launch_bounds__(512, 2) void gemm256(const ushort* __restrict__ A,
                                                  const ushort* __restrict__ B,
                                                  float* __restrict__ C, int M) {
  __shared__ ushort lds[65536];   // 128 KiB
  char* ldsb = (char*)lds;

  const int nmt = M >> 8;                    // 32 M-tiles
  const int nwg = gridDim.x;
  int wg = blockIdx.x;
  if ((nwg & 7) == 0) wg = (wg & 7) * (nwg >> 3) + (wg >> 3);   // XCD swizzle (bijective)
  const int bn = wg / nmt;                   // B panel L2-resident per XCD
  const int bm = wg % nmt;
  const int m0 = bm << 8, n0 = bn << 8;

  const int tid  = threadIdx.x;
  const int lane = tid & 63;
  const int wid  = tid >> 6;                 // 0..7
  const int wr   = wid >> 2;                 // 0..1: A 128-row half
  const int wc   = wid & 3;                  // 0..3: B 64-row stripe

  // staging geometry
  const int stRow = wid * 8 + (lane >> 3);   // + q*64
  const int sl    = (lane & 7) ^ (lane >> 3);

  // fragment geometry (32x32x16: row|col = lane&31, k = (lane>>5)*8 + e)
  const int lw = lane & 31;
  const int h  = lane >> 5;
  int kOff[4];
#pragma unroll
  for (int s = 0; s < 4; ++s) kOff[s] = ((2 * s + h) ^ (lane & 7)) << 4;

  f32x16 acc[4][2] = {};
  bf16x8 A_[2][4], B_[2][2];

  // ---- prologue: stage tiles 0,1; publish tile 0; preload slice0(0)
  STAGE_A(0, 0); STAGE_B(0, 0);
  STAGE_A(1, 1); STAGE_B(1, 1);
  asm volatile("s_waitcnt vmcnt(8)" ::: "memory");
  BAR();
  RD_SLICE(0, 0, ldsb + wr * 16384, ldsb + 32768 + wc * 8192);

#pragma unroll 1
  for (int t = 0; t < NT; ++t) {
    const int cur = t & 1, nxt = cur ^ 1;
    const char* aC = ldsb + cur * 65536 + wr * 16384;
    const char* bC = ldsb + cur * 65536 + 32768 + wc * 8192;
    const char* aN = ldsb + nxt * 65536 + wr * 16384;
    const char* bN = ldsb + nxt * 65536 + 32768 + wc * 8192;

    // ---- phase a: slices 0,1
    RD_SLICE(1, 1, aC, bC);        // s1 (lead-1, covered by s0 cluster)
    MFMA_SLICE(0);                 // s0
    RD_SLICE(0, 2, aC, bC);        // s2 (covered by s1 cluster)
    MFMA_SLICE(1);                 // s1
    BAR();                         // alpha: anti-drift fence (bounds wave skew)

    // ---- phase b: slices 2,3
    RD_SLICE(1, 3, aC, bC);        // s3 (A(t),B(t) last reads)
    if (t + 2 < NT) { STAGE_A(cur, t + 2); STAGE_B(cur, t + 2); }
    MFMA_SLICE(0);                 // s2
    if (t + 2 < NT)      { asm volatile("s_waitcnt vmcnt(8)" ::: "memory"); }
    else if (t + 1 < NT) { asm volatile("s_waitcnt vmcnt(0)" ::: "memory"); }
    BAR();                         // beta: publishes A(t+1),B(t+1)
    if (t + 1 < NT) RD_SLICE(0, 0, aN, bN);   // s0(t+1), covered by s3 cluster
    MFMA_SLICE(1);                 // s3
  }

  // ---- epilogue: 32x32 C/D map: col=lane&31, row=(reg&3)+8*(reg>>2)+4*h
  const int crow = m0 + wr * 128;
  const int ccol = n0 + wc * 64 + lw;
#pragma unroll
  for (int i = 0; i < 4; ++i)
#pragma unroll
    for (int j = 0; j < 2; ++j)
#pragma unroll
      for (int p = 0; p < 4; ++p)
#pragma unroll
        for (int q = 0; q < 4; ++q)
          C[(size_t)(crow + i * 32 + 8 * p + 4 * h + q) * OUT_F + (ccol + j * 32)] = acc[i][j][4 * p + q];
}

// ---- fallback: naive f32, correct but slow ------------------------------
__global__ void naive_kernel(const float* __restrict__ x, const int* __restrict__ cw,
                             const float* __restrict__ sc, const float* __restrict__ of,
                             float* __restrict__ out, int M) {
  int idx = blockIdx.x * blockDim.x + threadIdx.x;
  if (idx >= M * OUT_F) return;
  int o = idx & (OUT_F - 1);
  int m = idx >> 12;
  const float* xr = x + (size_t)m * IN_F;
  const int*   wr = cw + (size_t)o * IN_F;
  float acc = 0.f;
  for (int gg = 0; gg < NGROUPS; ++gg) {
    float s = sc[o * NGROUPS + gg], off = of[o * NGROUPS + gg];
#pragma unroll 8
    for (int k = 0; k < 128; ++k) {
      int kk = (gg << 7) + k;
      acc += xr[kk] * ((float)wr[kk] * s - off);
    }
  }
  out[idx] = acc;
}

extern "C" void kernel_launch(void* const* d_in, const int* in_sizes, int n_in,
                              void* d_out, int out_size, void* d_ws, size_t ws_size,
                              hipStream_t stream) {
  const float* x  = (const float*)d_in[0];
  const int*   cw = (const int*)d_in[1];
  const float* sc = (const float*)d_in[2];
  const float* of = (const float*)d_in[3];
  float* out = (float*)d_out;
  const int M = in_sizes[0] / IN_F;   // 8192

  const size_t xb_bytes = (size_t)M * IN_F * 2;
  const size_t wb_bytes = (size_t)OUT_F * IN_F * 2;

  if (ws_size >= xb_bytes + wb_bytes && (M % 256) == 0) {
    ushort* xb = (ushort*)d_ws;
    ushort* wb = (ushort*)((char*)d_ws + xb_bytes);

    int n8 = (M * IN_F) / 8;
    cvt_x_kernel<<<(n8 + 255) / 256, 256, 0, stream>>>(x, xb, n8);

    int nw8 = (OUT_F * IN_F) / 8;
    dequant_w_kernel<<<(nw8 + 255) / 256, 256, 0, stream>>>(cw, sc, of, wb);

    dim3 grid((M / 256) * (OUT_F / 256));   // 32 * 16 = 512
    gemm256<<<grid, 512, 0, stream>>>(xb, wb, out, M);
  } else {
    int total = M * OUT_F;
    naive_kernel<<<(total + 255) / 256, 256, 0, stream>>>(x, cw, sc, of, out, M);
  }
}

// Round 5
// 286.759 us; speedup vs baseline: 1.0937x; 1.0937x over previous
//
#include <hip/hip_runtime.h>
#include <stdint.h>

#define OUT_F 4096
#define IN_F  4096
#define NGROUPS 32
#define BK 64
#define NT (IN_F / BK)   // 64

typedef __attribute__((ext_vector_type(4)))  float    f32x4;
typedef __attribute__((ext_vector_type(8)))  short    bf16x8;
typedef __attribute__((ext_vector_type(4)))  int      i32x4;
typedef __attribute__((ext_vector_type(4)))  uint32_t u32x4;

__device__ __forceinline__ ushort f2bf(float f) {
  union { float f; uint32_t u; } v; v.f = f;
  uint32_t r = v.u + 0x7FFFu + ((v.u >> 16) & 1u);
  return (ushort)(r >> 16);
}

// ---- kernel 1: x (f32) -> bf16, 8 elems/thread --------------------------
__global__ void cvt_x_kernel(const float* __restrict__ x, ushort* __restrict__ xb, int n8) {
  int i = blockIdx.x * blockDim.x + threadIdx.x;
  if (i >= n8) return;
  const f32x4* xp = (const f32x4*)x;
  f32x4 a = xp[2 * i], b = xp[2 * i + 1];
  u32x4 o;
  o.x = (uint32_t)f2bf(a.x) | ((uint32_t)f2bf(a.y) << 16);
  o.y = (uint32_t)f2bf(a.z) | ((uint32_t)f2bf(a.w) << 16);
  o.z = (uint32_t)f2bf(b.x) | ((uint32_t)f2bf(b.y) << 16);
  o.w = (uint32_t)f2bf(b.z) | ((uint32_t)f2bf(b.w) << 16);
  ((u32x4*)xb)[i] = o;
}

// ---- kernel 2: dequant weight -> bf16 [OUT_F][IN_F] ----------------------
__global__ void dequant_w_kernel(const int* __restrict__ cw,
                                 const float* __restrict__ sc,
                                 const float* __restrict__ of,
                                 ushort* __restrict__ wb) {
  int t = blockIdx.x * blockDim.x + threadIdx.x;
  int o  = t >> 9;
  int k0 = (t & 511) << 3;
  int g  = k0 >> 7;
  float s   = sc[o * NGROUPS + g];
  float off = of[o * NGROUPS + g];
  const i32x4* cp = (const i32x4*)(cw + (size_t)o * IN_F + k0);
  i32x4 c0 = cp[0], c1 = cp[1];
  u32x4 out;
  out.x = (uint32_t)f2bf((float)c0.x * s - off) | ((uint32_t)f2bf((float)c0.y * s - off) << 16);
  out.y = (uint32_t)f2bf((float)c0.z * s - off) | ((uint32_t)f2bf((float)c0.w * s - off) << 16);
  out.z = (uint32_t)f2bf((float)c1.x * s - off) | ((uint32_t)f2bf((float)c1.y * s - off) << 16);
  out.w = (uint32_t)f2bf((float)c1.z * s - off) | ((uint32_t)f2bf((float)c1.w * s - off) << 16);
  *(u32x4*)(wb + (size_t)o * IN_F + k0) = out;
}

// ---- kernel 3: 256x256 tile, BK=64, 8-wave, 16x16x32, 8 half-clusters ----
// C[M][N] = A[M][K] * B[N][K]^T, bf16 in, f32 out.
// LDS 128KB: [buf(2)][A rows 0..255 | B rows 0..255], row = 128B (8 x 16B slots)
// swizzle: slot_phys = slot_log ^ (row&7) via pre-swizzled global source (R3-proven 0-conflict).
// 8 clusters/tile (8 MFMA each, one K-half); ALL fragment reads lead >= 1 cluster;
// 2 barriers + 2 counted vmcnt(4) per tile. Stage cadence: SA(t+2)@C6, SB(t+2)@C7.

#define BAR() do { asm volatile("" ::: "memory"); __builtin_amdgcn_s_barrier(); asm volatile("" ::: "memory"); } while (0)

#define GLLDS(gp, lp) __builtin_amdgcn_global_load_lds( \
  (const __attribute__((address_space(1))) uint32_t*)(const void*)(gp), \
  (__attribute__((address_space(3))) uint32_t*)(void*)(lp), 16, 0, 0)

#define STAGE_A(buf, kt) do { \
  _Pragma("unroll") for (int q_ = 0; q_ < 4; ++q_) \
    GLLDS(A + (size_t)(m0 + q_ * 64 + stRow) * IN_F + (kt) * BK + sl * 8, \
          ldsb + (buf) * 65536 + q_ * 8192 + wid * 1024); \
} while (0)

#define STAGE_B(buf, kt) do { \
  _Pragma("unroll") for (int q_ = 0; q_ < 4; ++q_) \
    GLLDS(B + (size_t)(n0 + q_ * 64 + stRow) * IN_F + (kt) * BK + sl * 8, \
          ldsb + (buf) * 65536 + 32768 + q_ * 8192 + wid * 1024); \
} while (0)

// read one K-half (H) of 4 A-frag-rows / 2 B-frag-cols
#define RD_AH(dst, i0, base, H, OFF) do { \
  _Pragma("unroll") for (int i_ = 0; i_ < 4; ++i_) \
    dst[i_][H] = *(const bf16x8*)((base) + ((i0) + i_) * 2048 + (OFF)); \
} while (0)

#define RD_BH(dst, j0, base, H, OFF) do { \
  _Pragma("unroll") for (int j_ = 0; j_ < 2; ++j_) \
    dst[j_][H] = *(const bf16x8*)((base) + ((j0) + j_) * 2048 + (OFF)); \
} while (0)

// one 8-MFMA cluster: quadrant (I0,J0), K-half H
#define MFMAH(I0, J0, Aset, Bset, H) do { \
  __builtin_amdgcn_s_setprio(1); \
  _Pragma("unroll") for (int i_ = 0; i_ < 4; ++i_) \
  _Pragma("unroll") for (int j_ = 0; j_ < 2; ++j_) \
    acc[(I0) + i_][(J0) + j_] = __builtin_amdgcn_mfma_f32_16x16x32_bf16(Aset[i_][H], Bset[j_][H], acc[(I0) + i_][(J0) + j_], 0, 0, 0); \
  __builtin_amdgcn_s_setprio(0); \
} while (0)

__global__ __launch_bounds__(512, 2) void gemm256(const ushort* __restrict__ A,
                                                  const ushort* __restrict__ B,
                                                  float* __restrict__ C, int M) {
  __shared__ ushort lds[65536];   // 128 KiB
  char* ldsb = (char*)lds;

  const int nmt = M >> 8;                    // 32 M-tiles
  const int nwg = gridDim.x;
  int wg = blockIdx.x;
  if ((nwg & 7) == 0) wg = (wg & 7) * (nwg >> 3) + (wg >> 3);   // XCD swizzle (bijective)
  const int bn = wg / nmt;                   // B panel L2-resident per XCD
  const int bm = wg % nmt;
  const int m0 = bm << 8, n0 = bn << 8;

  const int tid  = threadIdx.x;
  const int lane = tid & 63;
  const int wid  = tid >> 6;                 // 0..7
  const int wr   = wid >> 2;                 // 0..1: A 128-row half
  const int wc   = wid & 3;                  // 0..3: B 64-row stripe

  // staging geometry
  const int stRow = wid * 8 + (lane >> 3);   // + q*64
  const int sl    = (lane & 7) ^ (lane >> 3);

  // fragment geometry (16x16x32): row|col = lane&15, k = (lane>>4)*8 + e
  const int frow = lane & 15;
  const int g    = lane >> 4;                // 0..3
  const int off0 = frow * 128 + (((g    ) ^ (lane & 7)) << 4);  // K-half 0
  const int off1 = frow * 128 + (((4 + g) ^ (lane & 7)) << 4);  // K-half 1

  f32x4 acc[8][4] = {};
  bf16x8 A0_[4][2], A1_[4][2], B0_[2][2], B1_[2][2];

  // ---- prologue: stage tiles 0,1; publish tile 0; preload A0h0(0), B0h0(0)
  STAGE_A(0, 0); STAGE_B(0, 0);
  STAGE_A(1, 1); STAGE_B(1, 1);
  asm volatile("s_waitcnt vmcnt(8)" ::: "memory");
  BAR();
  RD_AH(A0_, 0, ldsb + wr * 16384, 0, off0);
  RD_BH(B0_, 0, ldsb + 32768 + wc * 8192, 0, off0);

#pragma unroll 1
  for (int t = 0; t < NT; ++t) {
    const int cur = t & 1, nxt = cur ^ 1;
    const char* aC = ldsb + cur * 65536 + wr * 16384;
    const char* bC = ldsb + cur * 65536 + 32768 + wc * 8192;
    const char* aN = ldsb + nxt * 65536 + wr * 16384;
    const char* bN = ldsb + nxt * 65536 + 32768 + wc * 8192;

    // C1: rd B1h0 (lead-1), A1h0 (lead-2) | Q00h0
    RD_BH(B1_, 2, bC, 0, off0);
    RD_AH(A1_, 4, aC, 0, off0);
    MFMAH(0, 0, A0_, B0_, 0);

    // C2: rd A0h1 (lead-3) | Q01h0
    RD_AH(A0_, 0, aC, 1, off1);
    MFMAH(0, 2, A0_, B1_, 0);

    // C3: rd B0h1 (lead-2) | Q10h0
    RD_BH(B0_, 0, bC, 1, off1);
    MFMAH(4, 0, A1_, B0_, 0);

    // C4: rd B1h1 (lead-2), A1h1 (lead-3) | Q11h0
    RD_BH(B1_, 2, bC, 1, off1);
    RD_AH(A1_, 4, aC, 1, off1);
    MFMAH(4, 2, A1_, B1_, 0);

    // C5: Q00h1; then drain LDS reads (A1h1 first-used post-barrier),
    //     retire SA(t+1), BAR_A publishes A(t+1)
    MFMAH(0, 0, A0_, B0_, 1);
    asm volatile("s_waitcnt lgkmcnt(0)" ::: "memory");
    if (t + 1 < NT) { asm volatile("s_waitcnt vmcnt(4)" ::: "memory"); }
    BAR();   // BAR_A

    // C6: rd A0'(t+1)h0 (lead-3); issue SA(t+2) into cur.A | Q01h1
    if (t + 1 < NT) RD_AH(A0_, 0, aN, 0, off0);
    if (t + 2 < NT) STAGE_A(cur, t + 2);
    MFMAH(0, 2, A0_, B1_, 1);
    if (t + 2 < NT)      { asm volatile("s_waitcnt vmcnt(4)" ::: "memory"); }
    else if (t + 1 < NT) { asm volatile("s_waitcnt vmcnt(0)" ::: "memory"); }
    BAR();   // BAR_B publishes B(t+1)

    // C7: rd B0'(t+1)h0 (lead-2); issue SB(t+2) into cur.B | Q10h1
    if (t + 1 < NT) RD_BH(B0_, 0, bN, 0, off0);
    if (t + 2 < NT) STAGE_B(cur, t + 2);
    MFMAH(4, 0, A1_, B0_, 1);

    // C8: Q11h1
    MFMAH(4, 2, A1_, B1_, 1);
  }

  // ---- epilogue: C/D layout col=lane&15, row=(lane>>4)*4+reg [m89-verified]
  const int crow0 = m0 + wr * 128 + (g << 2);
  const int ccol0 = n0 + wc * 64 + frow;
#pragma unroll
  for (int mf = 0; mf < 8; ++mf)
#pragma unroll
    for (int nf = 0; nf < 4; ++nf)
#pragma unroll
      for (int q = 0; q < 4; ++q)
        C[(size_t)(crow0 + mf * 16 + q) * OUT_F + (ccol0 + nf * 16)] = acc[mf][nf][q];
}

// ---- fallback: naive f32, correct but slow ------------------------------
__global__ void naive_kernel(const float* __restrict__ x, const int* __restrict__ cw,
                             const float* __restrict__ sc, const float* __restrict__ of,
                             float* __restrict__ out, int M) {
  int idx = blockIdx.x * blockDim.x + threadIdx.x;
  if (idx >= M * OUT_F) return;
  int o = idx & (OUT_F - 1);
  int m = idx >> 12;
  const float* xr = x + (size_t)m * IN_F;
  const int*   wr = cw + (size_t)o * IN_F;
  float acc = 0.f;
  for (int gg = 0; gg < NGROUPS; ++gg) {
    float s = sc[o * NGROUPS + gg], off = of[o * NGROUPS + gg];
#pragma unroll 8
    for (int k = 0; k < 128; ++k) {
      int kk = (gg << 7) + k;
      acc += xr[kk] * ((float)wr[kk] * s - off);
    }
  }
  out[idx] = acc;
}

extern "C" void kernel_launch(void* const* d_in, const int* in_sizes, int n_in,
                              void* d_out, int out_size, void* d_ws, size_t ws_size,
                              hipStream_t stream) {
  const float* x  = (const float*)d_in[0];
  const int*   cw = (const int*)d_in[1];
  const float* sc = (const float*)d_in[2];
  const float* of = (const float*)d_in[3];
  float* out = (float*)d_out;
  const int M = in_sizes[0] / IN_F;   // 8192

  const size_t xb_bytes = (size_t)M * IN_F * 2;
  const size_t wb_bytes = (size_t)OUT_F * IN_F * 2;

  if (ws_size >= xb_bytes + wb_bytes && (M % 256) == 0) {
    ushort* xb = (ushort*)d_ws;
    ushort* wb = (ushort*)((char*)d_ws + xb_bytes);

    int n8 = (M * IN_F) / 8;
    cvt_x_kernel<<<(n8 + 255) / 256, 256, 0, stream>>>(x, xb, n8);

    int nw8 = (OUT_F * IN_F) / 8;
    dequant_w_kernel<<<(nw8 + 255) / 256, 256, 0, stream>>>(cw, sc, of, wb);

    dim3 grid((M / 256) * (OUT_F / 256));   // 32 * 16 = 512
    gemm256<<<grid, 512, 0, stream>>>(xb, wb, out, M);
  } else {
    int total = M * OUT_F;
    naive_kernel<<<(total + 255) / 256, 256, 0, stream>>>(x, cw, sc, of, out, M);
  }
}